// Round 3
// baseline (236.739 us; speedup 1.0000x reference)
//
#include <hip/hip_runtime.h>

// LIF recurrence, T=4, TAU=1.0, THRESH=1.0.
// mem = mem + x[t]; spike = (mem - 1 > 0); mem = spike ? 0 : mem.
// Element-wise; one thread owns one 4-float column across all T timesteps.
//
// R1 fix: load all T float4s into DISTINCT registers before any compute/store
// (4 independent global loads in flight per wave, vs R0's serial
// load->waitcnt(0)->store chain through one reused reg quad at VGPR=16).
// R2 fix: use a native ext_vector_type for __builtin_nontemporal_store
// (HIP's float4 struct is rejected by the builtin).

#define LIF_T 4

typedef float v4f __attribute__((ext_vector_type(4)));

__global__ __launch_bounds__(256) void
lif_spike_kernel(const float* __restrict__ x, float* __restrict__ out, int n_vec, int n) {
    int v = blockIdx.x * blockDim.x + threadIdx.x;
    if (v >= n_vec) return;
    size_t i = (size_t)v * 4;

    // Phase 1: issue all loads (independent addresses, distinct registers).
    v4f xt[LIF_T];
#pragma unroll
    for (int t = 0; t < LIF_T; ++t) {
        xt[t] = *reinterpret_cast<const v4f*>(x + (size_t)t * n + i);
    }

    // Phase 2: compute the recurrence entirely in registers.
    v4f sp[LIF_T];
    v4f mem = (v4f)(0.0f);
#pragma unroll
    for (int t = 0; t < LIF_T; ++t) {
        mem += xt[t];
        v4f s;
        s.x = (mem.x > 1.0f) ? 1.0f : 0.0f;
        s.y = (mem.y > 1.0f) ? 1.0f : 0.0f;
        s.z = (mem.z > 1.0f) ? 1.0f : 0.0f;
        s.w = (mem.w > 1.0f) ? 1.0f : 0.0f;
        sp[t] = s;
        mem.x = (s.x > 0.f) ? 0.f : mem.x;
        mem.y = (s.y > 0.f) ? 0.f : mem.y;
        mem.z = (s.z > 0.f) ? 0.f : mem.z;
        mem.w = (s.w > 0.f) ? 0.f : mem.w;
    }

    // Phase 3: stream all stores out (write-once data -> nontemporal).
#pragma unroll
    for (int t = 0; t < LIF_T; ++t) {
        __builtin_nontemporal_store(sp[t], reinterpret_cast<v4f*>(out + (size_t)t * n + i));
    }
}

extern "C" void kernel_launch(void* const* d_in, const int* in_sizes, int n_in,
                              void* d_out, int out_size, void* d_ws, size_t ws_size,
                              hipStream_t stream) {
    const float* x = (const float*)d_in[0];
    float* out = (float*)d_out;

    int n = out_size / LIF_T;      // elements per timestep (8,388,608)
    int n_vec = n / 4;             // float4 groups per timestep

    int block = 256;
    int grid = (n_vec + block - 1) / block;
    lif_spike_kernel<<<grid, block, 0, stream>>>(x, out, n_vec, n);
}